// Round 2
// baseline (817.375 us; speedup 1.0000x reference)
//
#include <hip/hip_runtime.h>
#include <math.h>

#define NTRAIN 2000
#define DIMD 210
#define DIMI 63
#define NPERM 12
#define NCOLS 8
#define NATOM 21
#define SIGF 10.0f

// ---------------- setup kernel: build index tables in workspace ----------------
__global__ void gdml_setup(const int* __restrict__ tril, int* __restrict__ perm_idx,
                           int* __restrict__ invperm, int* __restrict__ pairRow,
                           int* __restrict__ pairCol, int* __restrict__ atomPairs,
                           float* __restrict__ atomSign) {
  int tid = threadIdx.x;
  // pair d -> (rowAtom, colAtom) for tril_indices(21, k=-1), row-major order
  for (int d = tid; d < DIMD; d += blockDim.x) {
    int a = 1;
    while ((a * (a + 1)) / 2 <= d) a++;
    int b = d - (a * (a - 1)) / 2;
    pairRow[d] = a;
    pairCol[d] = b;
  }
  // perm_idx[p][d] = tril[d*P + p] % D  (matches reference reshape(D,P).T % D)
  for (int idx = tid; idx < NPERM * DIMD; idx += blockDim.x) {
    int p = idx / DIMD, d = idx % DIMD;
    perm_idx[idx] = tril[d * NPERM + p] % DIMD;
  }
  __syncthreads();
  // inverse permutation per p
  for (int idx = tid; idx < NPERM * DIMD; idx += blockDim.x) {
    int p = idx / DIMD, d = idx % DIMD;
    invperm[p * DIMD + perm_idx[idx]] = d;
  }
  // per-atom pair lists: each atom participates in exactly 20 pairs
  if (tid < NATOM) {
    int t = tid, cnt = 0;
    for (int d = 0; d < DIMD; ++d) {
      if (pairRow[d] == t) { atomPairs[t * 20 + cnt] = d; atomSign[t * 20 + cnt] = 1.0f; cnt++; }
      else if (pairCol[d] == t) { atomPairs[t * 20 + cnt] = d; atomSign[t * 20 + cnt] = -1.0f; cnt++; }
    }
  }
}

// ---------------- main kernel: one block per (n, j-column) ----------------
__global__ __launch_bounds__(256) void gdml_main(
    const float* __restrict__ R_desc, const float* __restrict__ R_d_desc,
    const int* __restrict__ j_idxs, const int* __restrict__ perm_idx,
    const int* __restrict__ invperm, const int* __restrict__ pairRow,
    const int* __restrict__ pairCol, const int* __restrict__ atomPairs,
    const float* __restrict__ atomSign, float* __restrict__ out) {
  const int bid = blockIdx.x;
  const int jc = bid & 7;          // which of the 8 output column blocks
  const int n = bid >> 3;          // training point (row block)
  const int tid = threadIdx.x;
  const int j = j_idxs[jc];

  __shared__ float Rn[DIMD];           // R_desc[n]
  __shared__ float Rj[DIMD];           // R_desc[j]
  __shared__ float Rdn[DIMD * 3];      // R_d_desc[n] compact Jacobian
  __shared__ float Rdj[DIMD * 3];      // R_d_desc[j]
  __shared__ float diff[NPERM * DIMD]; // diff[p][d]
  __shared__ float bmat[NPERM * DIMI]; // b[p][e]
  __shared__ float Gmat[NPERM * DIMI]; // G[p][k]
  __shared__ float c1s[NPERM], c2s[NPERM];
  __shared__ float partial[NPERM * 21];
  __shared__ float H[DIMD * DIMI];     // H[d][e] = sum_p c2[p]*rj_d_perms[p,d,e]

  for (int i = tid; i < DIMD; i += 256) {
    Rn[i] = R_desc[(size_t)n * DIMD + i];
    Rj[i] = R_desc[(size_t)j * DIMD + i];
  }
  for (int i = tid; i < DIMD * 3; i += 256) {
    Rdn[i] = R_d_desc[(size_t)n * DIMD * 3 + i];
    Rdj[i] = R_d_desc[(size_t)j * DIMD * 3 + i];
  }
  __syncthreads();

  // diff[p][d] = R_desc[n][d] - R_desc[j][perm[p][d]]
  for (int idx = tid; idx < NPERM * DIMD; idx += 256) {
    int d = idx % DIMD;
    diff[idx] = Rn[d] - Rj[perm_idx[idx]];
  }
  __syncthreads();

  // per-p squared norms: 12 p's x 21 segments of 10
  if (tid < NPERM * 21) {
    int p = tid / 21, seg = tid % 21;
    const float* dp = &diff[p * DIMD + seg * 10];
    float s = 0.f;
#pragma unroll
    for (int i = 0; i < 10; ++i) s += dp[i] * dp[i];
    partial[tid] = s;
  }
  __syncthreads();
  if (tid < NPERM) {
    float s = 0.f;
#pragma unroll
    for (int i = 0; i < 21; ++i) s += partial[tid * 21 + i];
    float nrm = sqrtf(5.0f) * sqrtf(s);
    float mat52 = expf(-nrm / SIGF) * (5.0f / (3.0f * SIGF * SIGF * SIGF * SIGF));
    c1s[tid] = 5.0f * mat52;
    c2s[tid] = (SIGF * SIGF + SIGF * nrm) * mat52;
  }
  // zero H in the same phase
  for (int i = tid; i < DIMD * DIMI; i += 256) H[i] = 0.f;
  __syncthreads();

  // b[p,e] and G[p,k]: 20-entry gathers via per-atom pair lists.
  // NOTE: 756 work items > 256 threads -> MUST be a strided loop (round-1 bug).
  for (int idx = tid; idx < NPERM * DIMI; idx += 256) {
    int p = idx / DIMI, e = idx % DIMI;
    int at = e / 3, c = e % 3;
    const int* ap = &atomPairs[at * 20];
    const float* as = &atomSign[at * 20];
    const float* dfp = &diff[p * DIMD];
    const int* ivp = &invperm[p * DIMD];
    float bb = 0.f, gg = 0.f;
#pragma unroll
    for (int i = 0; i < 20; ++i) {
      int d = ap[i];
      float s = as[i];
      gg += s * Rdn[d * 3 + c] * dfp[d];
      bb += s * Rdj[d * 3 + c] * dfp[ivp[d]];
    }
    bmat[idx] = bb;
    Gmat[idx] = c1s[p] * gg;
  }
  // H[d][e]: thread d owns row d (no conflicts)
  if (tid < DIMD) {
    int d = tid;
    float* Hrow = &H[d * DIMI];
#pragma unroll
    for (int p = 0; p < NPERM; ++p) {
      int dd = perm_idx[p * DIMD + d];
      float w = c2s[p];
      int a = pairRow[dd], bt = pairCol[dd];
      float v0 = w * Rdj[dd * 3 + 0];
      float v1 = w * Rdj[dd * 3 + 1];
      float v2 = w * Rdj[dd * 3 + 2];
      Hrow[3 * a + 0] += v0; Hrow[3 * a + 1] += v1; Hrow[3 * a + 2] += v2;
      Hrow[3 * bt + 0] -= v0; Hrow[3 * bt + 1] -= v1; Hrow[3 * bt + 2] -= v2;
    }
  }
  __syncthreads();

  // kblk[k,e] = sum_p G[p,k]*b[p,e] - sum_{d in pairs(atom(k))} sign*Rdn[d,c]*H[d,e]
  float* outBase = out + (size_t)n * DIMI * (NCOLS * DIMI) + (size_t)jc * DIMI;
  for (int idx = tid; idx < DIMI * DIMI; idx += 256) {
    int k = idx / DIMI, e = idx % DIMI;
    int at = k / 3, c = k % 3;
    float acc = 0.f;
#pragma unroll
    for (int p = 0; p < NPERM; ++p) acc += Gmat[p * DIMI + k] * bmat[p * DIMI + e];
    const int* ap = &atomPairs[at * 20];
    const float* as = &atomSign[at * 20];
#pragma unroll
    for (int i = 0; i < 20; ++i) {
      int d = ap[i];
      acc -= as[i] * Rdn[d * 3 + c] * H[d * DIMI + e];
    }
    outBase[(size_t)k * (NCOLS * DIMI) + e] = acc;
  }
}

extern "C" void kernel_launch(void* const* d_in, const int* in_sizes, int n_in,
                              void* d_out, int out_size, void* d_ws, size_t ws_size,
                              hipStream_t stream) {
  const float* R_desc = (const float*)d_in[0];
  const float* R_d_desc = (const float*)d_in[1];
  const int* tril = (const int*)d_in[2];
  const int* j_idxs = (const int*)d_in[3];
  float* out = (float*)d_out;

  int* perm_idx = (int*)d_ws;                    // 12*210
  int* invperm = perm_idx + NPERM * DIMD;        // 12*210
  int* pairRow = invperm + NPERM * DIMD;         // 210
  int* pairCol = pairRow + DIMD;                 // 210
  int* atomPairs = pairCol + DIMD;               // 21*20
  float* atomSign = (float*)(atomPairs + NATOM * 20); // 21*20

  hipLaunchKernelGGL(gdml_setup, dim3(1), dim3(256), 0, stream,
                     tril, perm_idx, invperm, pairRow, pairCol, atomPairs, atomSign);
  hipLaunchKernelGGL(gdml_main, dim3(NTRAIN * NCOLS), dim3(256), 0, stream,
                     R_desc, R_d_desc, j_idxs, perm_idx, invperm, pairRow, pairCol,
                     atomPairs, atomSign, out);
}

// Round 3
// 769.702 us; speedup vs baseline: 1.0619x; 1.0619x over previous
//
#include <hip/hip_runtime.h>
#include <math.h>

#define NTRAIN 2000
#define DIMD 210
#define DIMI 63
#define NPERM 12
#define NCOLS 8
#define NATOM 21
#define SIGF 10.0f
#define HPAD 66   // padded H row stride (even -> float2 aligned, 2d+e bank spread)

// ---------------- setup: build packed index tables in workspace ----------------
// ws layout (ints): perm[2520] | invperm[2520] | pairRow[210] | pairCol[210] |
//                   atomPairs[420] | atomSignNeg[420] | pairsPacked[420] |
//                   gtab[5040] | permpack[2520]
__global__ void gdml_setup(const int* __restrict__ tril, int* __restrict__ ws) {
  int* perm      = ws;
  int* invperm   = perm + NPERM * DIMD;
  int* pairRow   = invperm + NPERM * DIMD;
  int* pairCol   = pairRow + DIMD;
  int* atomPairs = pairCol + DIMD;
  int* atomNeg   = atomPairs + NATOM * 20;
  int* pairsPk   = atomNeg + NATOM * 20;
  int* gtab      = pairsPk + NATOM * 20;
  int* permpack  = gtab + NPERM * NATOM * 20;

  int tid = threadIdx.x;
  // pair d -> (rowAtom, colAtom) for tril_indices(21, k=-1)
  for (int d = tid; d < DIMD; d += blockDim.x) {
    int a = 1;
    while ((a * (a + 1)) / 2 <= d) a++;
    int b = d - (a * (a - 1)) / 2;
    pairRow[d] = a;
    pairCol[d] = b;
  }
  // perm[p][d] = tril[d*P + p] % D
  for (int idx = tid; idx < NPERM * DIMD; idx += blockDim.x) {
    int p = idx / DIMD, d = idx % DIMD;
    perm[idx] = tril[d * NPERM + p] % DIMD;
  }
  __syncthreads();
  for (int idx = tid; idx < NPERM * DIMD; idx += blockDim.x) {
    int p = idx / DIMD;
    invperm[p * DIMD + perm[idx]] = idx % DIMD;
  }
  if (tid < NATOM) {
    int t = tid, cnt = 0;
    for (int d = 0; d < DIMD; ++d) {
      if (pairRow[d] == t)      { atomPairs[t * 20 + cnt] = d; atomNeg[t * 20 + cnt] = 0; cnt++; }
      else if (pairCol[d] == t) { atomPairs[t * 20 + cnt] = d; atomNeg[t * 20 + cnt] = 1; cnt++; }
    }
  }
  __syncthreads();
  // pairsPacked: d | neg<<16
  for (int idx = tid; idx < NATOM * 20; idx += blockDim.x)
    pairsPk[idx] = atomPairs[idx] | (atomNeg[idx] << 16);
  // gtab[(p*21+at)*20+i] = d | tw<<9 | neg<<18, tw = invperm[p][d]
  for (int idx = tid; idx < NPERM * NATOM * 20; idx += blockDim.x) {
    int p = idx / (NATOM * 20);
    int r = idx % (NATOM * 20);
    int d = atomPairs[r], neg = atomNeg[r];
    int tw = invperm[p * DIMD + d];
    gtab[idx] = d | (tw << 9) | (neg << 18);
  }
  // permpack[p*210+d] = dd | a<<8 | b<<16
  for (int idx = tid; idx < NPERM * DIMD; idx += blockDim.x) {
    int dd = perm[idx];
    permpack[idx] = dd | (pairRow[dd] << 8) | (pairCol[dd] << 16);
  }
}

// ---------------- main kernel: one block per (n, j-column) ----------------
__global__ __launch_bounds__(256) void gdml_main(
    const float* __restrict__ R_desc, const float* __restrict__ R_d_desc,
    const int* __restrict__ j_idxs, const int* __restrict__ ws,
    float* __restrict__ out) {
  const int* perm     = ws;
  const int* pairsPk  = ws + 2 * NPERM * DIMD + 2 * DIMD + 2 * NATOM * 20;
  const int* gtab     = pairsPk + NATOM * 20;
  const int* permpack = gtab + NPERM * NATOM * 20;

  const int bid = blockIdx.x;
  const int jc = bid & 7;
  const int n = bid >> 3;
  const int tid = threadIdx.x;
  const int j = j_idxs[jc];

  __shared__ __align__(16) float H[DIMD][HPAD];      // 55,440 B
  __shared__ __align__(16) float diffS[NPERM][DIMD]; // 10,080 B
  __shared__ __align__(16) float Rdn[DIMD * 3];      // 2,520
  __shared__ __align__(16) float Rdj[DIMD * 3];      // 2,520
  __shared__ __align__(16) float Rn[DIMD], Rj[DIMD]; // 1,680
  __shared__ __align__(16) float bT[DIMI][12];       // 3,024 (float4-aligned rows)
  __shared__ __align__(16) float GT[DIMI][12];       // 3,024
  __shared__ int   pairsL[NATOM * 20];               // 1,680
  __shared__ float c1s[NPERM], c2s[NPERM];
  __shared__ float partial[252];

  // ---- stage inputs + zero H ----
  for (int i = tid; i < DIMD; i += 256) {
    Rn[i] = R_desc[(size_t)n * DIMD + i];
    Rj[i] = R_desc[(size_t)j * DIMD + i];
  }
  for (int i = tid; i < DIMD * 3; i += 256) {
    Rdn[i] = R_d_desc[(size_t)n * DIMD * 3 + i];
    Rdj[i] = R_d_desc[(size_t)j * DIMD * 3 + i];
  }
  for (int i = tid; i < NATOM * 20; i += 256) pairsL[i] = pairsPk[i];
  {
    float2* Hz = (float2*)&H[0][0];
    for (int i = tid; i < DIMD * HPAD / 2; i += 256) Hz[i] = make_float2(0.f, 0.f);
  }
  __syncthreads();

  // ---- diff[p][d] = Rn[d] - Rj[perm[p][d]] ----
  for (int idx = tid; idx < NPERM * DIMD; idx += 256) {
    int d = idx % DIMD;
    ((float*)diffS)[idx] = Rn[d] - Rj[perm[idx]];
  }
  __syncthreads();

  // ---- norms ----
  if (tid < 252) {
    int p = tid / 21, seg = tid % 21;
    const float* dp = &diffS[p][seg * 10];
    float s = 0.f;
#pragma unroll
    for (int i = 0; i < 10; ++i) s += dp[i] * dp[i];
    partial[tid] = s;
  }
  __syncthreads();
  if (tid < NPERM) {
    float s = 0.f;
#pragma unroll
    for (int i = 0; i < 21; ++i) s += partial[tid * 21 + i];
    float nrm = sqrtf(5.0f) * sqrtf(s);
    float mat52 = expf(-nrm / SIGF) * (5.0f / (3.0f * SIGF * SIGF * SIGF * SIGF));
    c1s[tid] = 5.0f * mat52;
    c2s[tid] = (SIGF * SIGF + SIGF * nrm) * mat52;
  }
  __syncthreads();

  // ---- b/G: thread = (p, at); 3 outputs each of b and G ----
  if (tid < NPERM * NATOM) {
    int p = tid / NATOM, at = tid % NATOM;
    const int* gt = &gtab[(p * NATOM + at) * 20];
    const float* dfp = &diffS[p][0];
    float g0 = 0, g1 = 0, g2 = 0, b0 = 0, b1 = 0, b2 = 0;
#pragma unroll
    for (int i = 0; i < 20; ++i) {
      int v = gt[i];
      int d = v & 511, tw = (v >> 9) & 511;
      float s = (v & (1 << 18)) ? -1.0f : 1.0f;
      float fd = s * dfp[d], ftw = s * dfp[tw];
      g0 += Rdn[3 * d + 0] * fd;
      g1 += Rdn[3 * d + 1] * fd;
      g2 += Rdn[3 * d + 2] * fd;
      b0 += Rdj[3 * d + 0] * ftw;
      b1 += Rdj[3 * d + 1] * ftw;
      b2 += Rdj[3 * d + 2] * ftw;
    }
    float c1 = c1s[p];
    GT[3 * at + 0][p] = c1 * g0;
    GT[3 * at + 1][p] = c1 * g1;
    GT[3 * at + 2][p] = c1 * g2;
    bT[3 * at + 0][p] = b0;
    bT[3 * at + 1][p] = b1;
    bT[3 * at + 2][p] = b2;
  }
  // ---- H assembly: thread d owns row d ----
  if (tid < DIMD) {
    float* Hrow = &H[tid][0];
#pragma unroll
    for (int p = 0; p < NPERM; ++p) {
      int v = permpack[p * DIMD + tid];
      int dd = v & 255, a = (v >> 8) & 31, b = (v >> 16) & 31;
      float w = c2s[p];
      float v0 = w * Rdj[3 * dd + 0];
      float v1 = w * Rdj[3 * dd + 1];
      float v2 = w * Rdj[3 * dd + 2];
      Hrow[3 * a + 0] += v0; Hrow[3 * a + 1] += v1; Hrow[3 * a + 2] += v2;
      Hrow[3 * b + 0] -= v0; Hrow[3 * b + 1] -= v1; Hrow[3 * b + 2] -= v2;
    }
  }
  __syncthreads();

  // ---- final: thread = (at, echunk); 3 k-rows x 6 e-cols register tile ----
  if (tid < 252) {
    int at = tid / 12, ec = tid % 12;
    int e0 = ec * 6;  // even -> float2 aligned

    float Gr[3][12];
#pragma unroll
    for (int c = 0; c < 3; ++c) {
      const float4* gp = (const float4*)&GT[3 * at + c][0];
      float4 a0 = gp[0], a1 = gp[1], a2 = gp[2];
      Gr[c][0] = a0.x; Gr[c][1] = a0.y; Gr[c][2] = a0.z; Gr[c][3] = a0.w;
      Gr[c][4] = a1.x; Gr[c][5] = a1.y; Gr[c][6] = a1.z; Gr[c][7] = a1.w;
      Gr[c][8] = a2.x; Gr[c][9] = a2.y; Gr[c][10] = a2.z; Gr[c][11] = a2.w;
    }
    float acc[3][6];
#pragma unroll
    for (int c = 0; c < 3; ++c)
#pragma unroll
      for (int ee = 0; ee < 6; ++ee) acc[c][ee] = 0.f;

    // term1: G^T b outer products over 12 perms
#pragma unroll
    for (int ee = 0; ee < 6; ++ee) {
      int e = e0 + ee; e = e < DIMI ? e : DIMI - 1;  // clamped lanes compute junk, never written
      const float4* bp = (const float4*)&bT[e][0];
      float4 v0 = bp[0], v1 = bp[1], v2 = bp[2];
      float br[12] = {v0.x, v0.y, v0.z, v0.w, v1.x, v1.y, v1.z, v1.w,
                      v2.x, v2.y, v2.z, v2.w};
#pragma unroll
      for (int c = 0; c < 3; ++c) {
        float a = 0.f;
#pragma unroll
        for (int p = 0; p < 12; ++p) a += Gr[c][p] * br[p];
        acc[c][ee] += a;
      }
    }

    // term2: minus 20-pair gather against H (sign folded: s here = -sign)
    const int* pl = &pairsL[at * 20];
#pragma unroll
    for (int i = 0; i < 20; ++i) {
      int v = pl[i];
      int d = v & 0xFFFF;
      float s = (v & 0x10000) ? 1.0f : -1.0f;
      float w0 = s * Rdn[3 * d + 0];
      float w1 = s * Rdn[3 * d + 1];
      float w2 = s * Rdn[3 * d + 2];
      const float2* hp = (const float2*)&H[d][e0];
      float2 h0 = hp[0], h1 = hp[1], h2 = hp[2];
      acc[0][0] += w0 * h0.x; acc[0][1] += w0 * h0.y;
      acc[0][2] += w0 * h1.x; acc[0][3] += w0 * h1.y;
      acc[0][4] += w0 * h2.x; acc[0][5] += w0 * h2.y;
      acc[1][0] += w1 * h0.x; acc[1][1] += w1 * h0.y;
      acc[1][2] += w1 * h1.x; acc[1][3] += w1 * h1.y;
      acc[1][4] += w1 * h2.x; acc[1][5] += w1 * h2.y;
      acc[2][0] += w2 * h0.x; acc[2][1] += w2 * h0.y;
      acc[2][2] += w2 * h1.x; acc[2][3] += w2 * h1.y;
      acc[2][4] += w2 * h2.x; acc[2][5] += w2 * h2.y;
    }

    size_t base = (size_t)n * DIMI * (NCOLS * DIMI) + (size_t)jc * DIMI;
#pragma unroll
    for (int c = 0; c < 3; ++c) {
      int k = 3 * at + c;
      float* op = out + base + (size_t)k * (NCOLS * DIMI) + e0;
#pragma unroll
      for (int ee = 0; ee < 6; ++ee)
        if (e0 + ee < DIMI) op[ee] = acc[c][ee];
    }
  }
}

extern "C" void kernel_launch(void* const* d_in, const int* in_sizes, int n_in,
                              void* d_out, int out_size, void* d_ws, size_t ws_size,
                              hipStream_t stream) {
  const float* R_desc = (const float*)d_in[0];
  const float* R_d_desc = (const float*)d_in[1];
  const int* tril = (const int*)d_in[2];
  const int* j_idxs = (const int*)d_in[3];
  float* out = (float*)d_out;
  int* ws = (int*)d_ws;

  hipLaunchKernelGGL(gdml_setup, dim3(1), dim3(256), 0, stream, tril, ws);
  hipLaunchKernelGGL(gdml_main, dim3(NTRAIN * NCOLS), dim3(256), 0, stream,
                     R_desc, R_d_desc, j_idxs, ws, out);
}

// Round 4
// 704.641 us; speedup vs baseline: 1.1600x; 1.0923x over previous
//
#include <hip/hip_runtime.h>
#include <math.h>

#define NTRAIN 2000
#define DIMD 210
#define DIMI 63
#define NPERM 12
#define NCOLS 8
#define NATOM 21
#define SIGF 10.0f

// ws layout (ints):
// perm[2520] invperm[2520] pairRow[210] pairCol[210] atomPairs[420] atomNeg[420]
// gtab[5040] entOff[442] ents[10080] cnt[441]
#define WS_PERM      0
#define WS_INVPERM   2520
#define WS_PAIRROW   5040
#define WS_PAIRCOL   5250
#define WS_ATOMPAIRS 5460
#define WS_ATOMNEG   5880
#define WS_GTAB      6300
#define WS_ENTOFF    11340
#define WS_ENTS      11782
#define WS_CNT       21862

// ---------------- setup: build packed index tables + CSR entry lists ----------------
__global__ void gdml_setup(const int* __restrict__ tril, int* __restrict__ ws) {
  int* perm      = ws + WS_PERM;
  int* invperm   = ws + WS_INVPERM;
  int* pairRow   = ws + WS_PAIRROW;
  int* pairCol   = ws + WS_PAIRCOL;
  int* atomPairs = ws + WS_ATOMPAIRS;
  int* atomNeg   = ws + WS_ATOMNEG;
  int* gtab      = ws + WS_GTAB;
  int* entOff    = ws + WS_ENTOFF;
  int* ents      = ws + WS_ENTS;
  int* cnt       = ws + WS_CNT;

  int tid = threadIdx.x;
  // pair d -> (rowAtom, colAtom) for tril_indices(21, k=-1)
  for (int d = tid; d < DIMD; d += blockDim.x) {
    int a = 1;
    while ((a * (a + 1)) / 2 <= d) a++;
    pairRow[d] = a;
    pairCol[d] = d - (a * (a - 1)) / 2;
  }
  // perm[p][d] = tril[d*P + p] % D
  for (int idx = tid; idx < NPERM * DIMD; idx += blockDim.x) {
    int p = idx / DIMD, d = idx % DIMD;
    perm[idx] = tril[d * NPERM + p] % DIMD;
  }
  __syncthreads();
  for (int idx = tid; idx < NPERM * DIMD; idx += blockDim.x) {
    int p = idx / DIMD;
    invperm[p * DIMD + perm[idx]] = idx % DIMD;
  }
  if (tid < NATOM) {
    int t = tid, c = 0;
    for (int d = 0; d < DIMD; ++d) {
      if (pairRow[d] == t)      { atomPairs[t * 20 + c] = d; atomNeg[t * 20 + c] = 0; c++; }
      else if (pairCol[d] == t) { atomPairs[t * 20 + c] = d; atomNeg[t * 20 + c] = 1; c++; }
    }
  }
  __syncthreads();
  // gtab[(p*21+at)*20+i] = d | tw<<9 | neg<<18   (for the b/G phase)
  for (int idx = tid; idx < NPERM * NATOM * 20; idx += blockDim.x) {
    int p = idx / (NATOM * 20);
    int r = idx % (NATOM * 20);
    int d = atomPairs[r], neg = atomNeg[r];
    int tw = invperm[p * DIMD + d];
    gtab[idx] = d | (tw << 9) | (neg << 18);
  }
  // counts for CSR: (A,B) gets one entry per (i,p) where perm maps d into a pair touching B
  for (int q = tid; q < NATOM * NATOM; q += blockDim.x) {
    int A = q / NATOM, B = q % NATOM, c = 0;
    for (int i = 0; i < 20; ++i) {
      int d = atomPairs[A * 20 + i];
      for (int p = 0; p < NPERM; ++p) {
        int dd = perm[p * DIMD + d];
        c += (pairRow[dd] == B) + (pairCol[dd] == B);
      }
    }
    cnt[q] = c;
  }
  __syncthreads();
  if (tid == 0) {
    entOff[0] = 0;
    for (int q = 0; q < NATOM * NATOM; ++q) entOff[q + 1] = entOff[q] + cnt[q];
  }
  __syncthreads();
  // fill: ent = d | dd<<8 | p<<16 | negFlag<<20, negFlag = (sA*sB < 0)
  for (int q = tid; q < NATOM * NATOM; q += blockDim.x) {
    int A = q / NATOM, B = q % NATOM;
    int o = entOff[q];
    for (int i = 0; i < 20; ++i) {
      int d = atomPairs[A * 20 + i];
      int negA = atomNeg[A * 20 + i];  // 1 means sA = -1
      for (int p = 0; p < NPERM; ++p) {
        int dd = perm[p * DIMD + d];
        if (pairRow[dd] == B)  // sB = +1
          ents[o++] = d | (dd << 8) | (p << 16) | (negA << 20);
        if (pairCol[dd] == B)  // sB = -1
          ents[o++] = d | (dd << 8) | (p << 16) | ((1 - negA) << 20);
      }
    }
  }
}

// ---------------- main kernel: one block per (n, j-column) ----------------
__global__ __launch_bounds__(256, 4) void gdml_main(
    const float* __restrict__ R_desc, const float* __restrict__ R_d_desc,
    const int* __restrict__ j_idxs, const int* __restrict__ ws,
    float* __restrict__ out) {
  const int* perm   = ws + WS_PERM;
  const int* gtab   = ws + WS_GTAB;
  const int* entOff = ws + WS_ENTOFF;
  const int* ents   = ws + WS_ENTS;

  const int bid = blockIdx.x;
  const int jc = bid & 7;
  const int n = bid >> 3;
  const int tid = threadIdx.x;
  const int j = j_idxs[jc];

  __shared__ __align__(16) float diffS[NPERM][DIMD]; // 10,080 B
  __shared__ __align__(16) float4 Rdn4[DIMD];        // 3,360
  __shared__ __align__(16) float4 Rdj4[DIMD];        // 3,360
  __shared__ __align__(16) float Rn[DIMD], Rj[DIMD]; // 1,680
  __shared__ __align__(16) float GT[DIMI][12];       // 3,024 (rows 48B, float4-aligned)
  __shared__ __align__(16) float bT[DIMI][12];       // 3,024
  __shared__ float c1s[NPERM], c2s[NPERM];           // 96
  __shared__ float partial[252];                     // 1,008
  // total ~25.7 KB -> 5-6 blocks/CU

  // ---- stage inputs ----
  for (int i = tid; i < DIMD; i += 256) {
    Rn[i] = R_desc[(size_t)n * DIMD + i];
    Rj[i] = R_desc[(size_t)j * DIMD + i];
  }
  if (tid < DIMD) {
    const float* gn = &R_d_desc[(size_t)n * DIMD * 3 + 3 * tid];
    const float* gj = &R_d_desc[(size_t)j * DIMD * 3 + 3 * tid];
    Rdn4[tid] = make_float4(gn[0], gn[1], gn[2], 0.f);
    Rdj4[tid] = make_float4(gj[0], gj[1], gj[2], 0.f);
  }
  __syncthreads();

  // ---- diff[p][d] = Rn[d] - Rj[perm[p][d]] ----
  for (int idx = tid; idx < NPERM * DIMD; idx += 256) {
    int d = idx % DIMD;
    ((float*)diffS)[idx] = Rn[d] - Rj[perm[idx]];
  }
  __syncthreads();

  // ---- norms ----
  if (tid < 252) {
    int p = tid / 21, seg = tid % 21;
    const float* dp = &diffS[p][seg * 10];
    float s = 0.f;
#pragma unroll
    for (int i = 0; i < 10; ++i) s += dp[i] * dp[i];
    partial[tid] = s;
  }
  __syncthreads();
  if (tid < NPERM) {
    float s = 0.f;
#pragma unroll
    for (int i = 0; i < 21; ++i) s += partial[tid * 21 + i];
    float nrm = sqrtf(5.0f) * sqrtf(s);
    float mat52 = expf(-nrm / SIGF) * (5.0f / (3.0f * SIGF * SIGF * SIGF * SIGF));
    c1s[tid] = 5.0f * mat52;
    c2s[tid] = (SIGF * SIGF + SIGF * nrm) * mat52;
  }
  __syncthreads();

  // ---- b/G: thread = (p, at) ----
  if (tid < NPERM * NATOM) {
    int p = tid / NATOM, at = tid % NATOM;
    const int* gt = &gtab[(p * NATOM + at) * 20];
    const float* dfp = &diffS[p][0];
    float g0 = 0, g1 = 0, g2 = 0, b0 = 0, b1 = 0, b2 = 0;
#pragma unroll
    for (int i = 0; i < 20; ++i) {
      int v = gt[i];
      int d = v & 511, tw = (v >> 9) & 511;
      float s = (v & (1 << 18)) ? -1.0f : 1.0f;
      float fd = s * dfp[d], ftw = s * dfp[tw];
      float4 rn = Rdn4[d];
      float4 rj = Rdj4[d];
      g0 += rn.x * fd; g1 += rn.y * fd; g2 += rn.z * fd;
      b0 += rj.x * ftw; b1 += rj.y * ftw; b2 += rj.z * ftw;
    }
    float c1 = c1s[p];
    GT[3 * at + 0][p] = c1 * g0;
    GT[3 * at + 1][p] = c1 * g1;
    GT[3 * at + 2][p] = c1 * g2;
    bT[3 * at + 0][p] = b0;
    bT[3 * at + 1][p] = b1;
    bT[3 * at + 2][p] = b2;
  }
  __syncthreads();

  // ---- final: thread = one (A,B) 3x3 atom tile; term2 via CSR entries, term1 via G^T b ----
  const size_t base = (size_t)n * DIMI * (NCOLS * DIMI) + (size_t)jc * DIMI;
#pragma unroll
  for (int pass = 0; pass < 2; ++pass) {
    int pid = tid + pass * 252;
    if (tid < 252 && pid < NATOM * NATOM) {
      int A = pid / NATOM, B = pid % NATOM;
      float acc[3][3];
#pragma unroll
      for (int c = 0; c < 3; ++c)
#pragma unroll
        for (int e = 0; e < 3; ++e) acc[c][e] = 0.f;

      // term2 (minus folded into coef): acc -= sA*sB * c2[p] * Rdn[d,:] (x) Rdj[dd,:]
      int o0 = entOff[pid], o1 = entOff[pid + 1];
      for (int o = o0; o < o1; ++o) {
        int v = ents[o];
        int d = v & 255, dd = (v >> 8) & 255, p = (v >> 16) & 15;
        float c2 = c2s[p];
        float coef = (v & (1 << 20)) ? c2 : -c2;
        float4 rn = Rdn4[d];
        float4 rj = Rdj4[dd];
        float w0 = coef * rj.x, w1 = coef * rj.y, w2 = coef * rj.z;
        acc[0][0] += rn.x * w0; acc[0][1] += rn.x * w1; acc[0][2] += rn.x * w2;
        acc[1][0] += rn.y * w0; acc[1][1] += rn.y * w1; acc[1][2] += rn.y * w2;
        acc[2][0] += rn.z * w0; acc[2][1] += rn.z * w1; acc[2][2] += rn.z * w2;
      }

      // term1: acc[cg][cb] += sum_p G[3A+cg][p] * b[3B+cb][p]
#pragma unroll
      for (int cg = 0; cg < 3; ++cg) {
        const float4* gp = (const float4*)&GT[3 * A + cg][0];
        float4 ga = gp[0], gb = gp[1], gc = gp[2];
#pragma unroll
        for (int cb = 0; cb < 3; ++cb) {
          const float4* bp = (const float4*)&bT[3 * B + cb][0];
          float4 ba = bp[0], bb = bp[1], bc = bp[2];
          acc[cg][cb] += ga.x * ba.x + ga.y * ba.y + ga.z * ba.z + ga.w * ba.w
                       + gb.x * bb.x + gb.y * bb.y + gb.z * bb.z + gb.w * bb.w
                       + gc.x * bc.x + gc.y * bc.y + gc.z * bc.z + gc.w * bc.w;
        }
      }

      // write 3x3 tile
#pragma unroll
      for (int cg = 0; cg < 3; ++cg) {
        float* op = out + base + (size_t)(3 * A + cg) * (NCOLS * DIMI) + 3 * B;
        op[0] = acc[cg][0]; op[1] = acc[cg][1]; op[2] = acc[cg][2];
      }
    }
  }
}

extern "C" void kernel_launch(void* const* d_in, const int* in_sizes, int n_in,
                              void* d_out, int out_size, void* d_ws, size_t ws_size,
                              hipStream_t stream) {
  const float* R_desc = (const float*)d_in[0];
  const float* R_d_desc = (const float*)d_in[1];
  const int* tril = (const int*)d_in[2];
  const int* j_idxs = (const int*)d_in[3];
  float* out = (float*)d_out;
  int* ws = (int*)d_ws;

  hipLaunchKernelGGL(gdml_setup, dim3(1), dim3(256), 0, stream, tril, ws);
  hipLaunchKernelGGL(gdml_main, dim3(NTRAIN * NCOLS), dim3(256), 0, stream,
                     R_desc, R_d_desc, j_idxs, ws, out);
}

// Round 5
// 696.469 us; speedup vs baseline: 1.1736x; 1.0117x over previous
//
#include <hip/hip_runtime.h>
#include <math.h>

#define NTRAIN 2000
#define DIMD 210
#define DIMI 63
#define NPERM 12
#define NCOLS 8
#define NATOM 21
#define SIGF 10.0f

// ws layout (ints) — offsets kept compatible with R4:
// perm[2520] invperm[2520] pairRow[210] pairCol[210] atomPairs[420] atomNeg[420]
// gtab[5040] entOff[442] ents[10080]
#define WS_PERM      0
#define WS_INVPERM   2520
#define WS_PAIRROW   5040
#define WS_PAIRCOL   5250
#define WS_ATOMPAIRS 5460
#define WS_ATOMNEG   5880
#define WS_GTAB      6300
#define WS_ENTOFF    11340
#define WS_ENTS      11782
// total 21862 ints (~87 KB)

// ---------------- setup: fully parallel, LDS-staged (was ~200us serial) ----------------
__global__ __launch_bounds__(512) void gdml_setup(const int* __restrict__ tril,
                                                  int* __restrict__ ws) {
  __shared__ int sPerm[NPERM * DIMD];   // 10,080 B
  __shared__ int sInv[NPERM * DIMD];    // 10,080 B
  __shared__ int sRow[DIMD], sCol[DIMD];
  __shared__ int sPairs[NATOM * 20], sNeg[NATOM * 20];
  __shared__ int sCnt[441];
  __shared__ int sScan[512];
  __shared__ int sOff[442];

  const int tid = threadIdx.x;

  // pair d -> (rowAtom, colAtom)
  for (int d = tid; d < DIMD; d += 512) {
    int a = 1;
    while ((a * (a + 1)) / 2 <= d) a++;
    sRow[d] = a;
    sCol[d] = d - (a * (a - 1)) / 2;
  }
  // perm[p][d] = tril[d*P + p] % D
  for (int idx = tid; idx < NPERM * DIMD; idx += 512) {
    int p = idx / DIMD, d = idx % DIMD;
    sPerm[idx] = tril[d * NPERM + p] % DIMD;
  }
  __syncthreads();
  for (int idx = tid; idx < NPERM * DIMD; idx += 512) {
    int p = idx / DIMD;
    sInv[p * DIMD + sPerm[idx]] = idx % DIMD;
  }
  if (tid < NATOM) {
    int t = tid, c = 0;
    for (int d = 0; d < DIMD; ++d) {
      if (sRow[d] == t)      { sPairs[t * 20 + c] = d; sNeg[t * 20 + c] = 0; c++; }
      else if (sCol[d] == t) { sPairs[t * 20 + c] = d; sNeg[t * 20 + c] = 1; c++; }
    }
  }
  __syncthreads();

  // export perm (main's diff phase reads it)
  for (int idx = tid; idx < NPERM * DIMD; idx += 512) ws[WS_PERM + idx] = sPerm[idx];
  // gtab[(p*21+at)*20+i] = d | tw<<9 | neg<<18   (b/G phase, unchanged format)
  for (int idx = tid; idx < NPERM * NATOM * 20; idx += 512) {
    int p = idx / (NATOM * 20);
    int r = idx % (NATOM * 20);
    int d = sPairs[r], neg = sNeg[r];
    int tw = sInv[p * DIMD + d];
    ws[WS_GTAB + idx] = d | (tw << 9) | (neg << 18);
  }

  // CSR counts per (A,B) pid — all LDS reads
  for (int q = tid; q < 441; q += 512) {
    int A = q / NATOM, B = q % NATOM, c = 0;
    for (int i = 0; i < 20; ++i) {
      int d = sPairs[A * 20 + i];
      for (int p = 0; p < NPERM; ++p) {
        int dd = sPerm[p * DIMD + d];
        c += (sRow[dd] == B) + (sCol[dd] == B);
      }
    }
    sCnt[q] = c;
  }
  __syncthreads();

  // Hillis-Steele inclusive scan over 441 (padded to 512)
  sScan[tid] = (tid < 441) ? sCnt[tid] : 0;
  __syncthreads();
  for (int s = 1; s < 512; s <<= 1) {
    int v = (tid >= s) ? sScan[tid - s] : 0;
    __syncthreads();
    sScan[tid] += v;
    __syncthreads();
  }
  if (tid == 0) sOff[0] = 0;
  if (tid < 441) sOff[tid + 1] = sScan[tid];
  __syncthreads();
  for (int q = tid; q < 442; q += 512) ws[WS_ENTOFF + q] = sOff[q];

  // fill entries: v = (3d) | (3dd)<<10 | p<<20 | negbit<<24  (negbit=1 -> coef = -c2)
  for (int q = tid; q < 441; q += 512) {
    int A = q / NATOM, B = q % NATOM;
    int o = sOff[q];
    for (int i = 0; i < 20; ++i) {
      int d = sPairs[A * 20 + i];
      int negA = sNeg[A * 20 + i];
      for (int p = 0; p < NPERM; ++p) {
        int dd = sPerm[p * DIMD + d];
        int base = (3 * d) | ((3 * dd) << 10) | (p << 20);
        // R4-verified sign mapping: row target oldflag=negA, col target oldflag=1-negA,
        // coef = oldflag ? +c2 : -c2  =>  negbit = oldflag^1
        if (sRow[dd] == B) ws[WS_ENTS + (o++)] = base | ((negA ^ 1) << 24);
        if (sCol[dd] == B) ws[WS_ENTS + (o++)] = base | (negA << 24);
      }
    }
  }
}

// ---------------- main kernel: one block per (n, j-column) ----------------
__global__ __launch_bounds__(256, 4) void gdml_main(
    const float* __restrict__ R_desc, const float* __restrict__ R_d_desc,
    const int* __restrict__ j_idxs, const int* __restrict__ ws,
    float* __restrict__ out) {
  const int* perm   = ws + WS_PERM;
  const int* gtab   = ws + WS_GTAB;
  const int* entOff = ws + WS_ENTOFF;
  const int* ents   = ws + WS_ENTS;

  const int bid = blockIdx.x;
  const int jc = bid & 7;
  const int n = bid >> 3;
  const int tid = threadIdx.x;
  const int j = j_idxs[jc];

  __shared__ __align__(16) float diffS[NPERM][DIMD]; // 10,080 B
  __shared__ __align__(16) float4 Rdn4[DIMD];        // 3,360 (b/G phase)
  __shared__ __align__(16) float4 Rdj4[DIMD];        // 3,360 (b/G phase)
  __shared__ __align__(16) float Rn[DIMD];           // 840
  __shared__ __align__(16) float GT[DIMI][12];       // 3,024
  __shared__ __align__(16) float bT[DIMI][12];       // 3,024
  __shared__ float c1s[NPERM], c2s[NPERM];
  __shared__ float partial[252];
  // ~25.1 KB

  const float* gn = R_d_desc + (size_t)n * (DIMD * 3);  // L1-hot row (2.5 KB)
  const float* gj = R_d_desc + (size_t)j * (DIMD * 3);
  const float* gRj = R_desc + (size_t)j * DIMD;         // L1-hot (840 B)

  // ---- stage inputs ----
  for (int i = tid; i < DIMD; i += 256) Rn[i] = R_desc[(size_t)n * DIMD + i];
  if (tid < DIMD) {
    Rdn4[tid] = make_float4(gn[3 * tid], gn[3 * tid + 1], gn[3 * tid + 2], 0.f);
    Rdj4[tid] = make_float4(gj[3 * tid], gj[3 * tid + 1], gj[3 * tid + 2], 0.f);
  }
  __syncthreads();

  // ---- diff[p][d] = Rn[d] - Rj[perm[p][d]]  (Rj read from global/L1) ----
  for (int idx = tid; idx < NPERM * DIMD; idx += 256) {
    int d = idx % DIMD;
    ((float*)diffS)[idx] = Rn[d] - gRj[perm[idx]];
  }
  __syncthreads();

  // ---- norms ----
  if (tid < 252) {
    int p = tid / 21, seg = tid % 21;
    const float* dp = &diffS[p][seg * 10];
    float s = 0.f;
#pragma unroll
    for (int i = 0; i < 10; ++i) s += dp[i] * dp[i];
    partial[tid] = s;
  }
  __syncthreads();
  if (tid < NPERM) {
    float s = 0.f;
#pragma unroll
    for (int i = 0; i < 21; ++i) s += partial[tid * 21 + i];
    float nrm = sqrtf(5.0f) * sqrtf(s);
    float mat52 = expf(-nrm / SIGF) * (5.0f / (3.0f * SIGF * SIGF * SIGF * SIGF));
    c1s[tid] = 5.0f * mat52;
    c2s[tid] = (SIGF * SIGF + SIGF * nrm) * mat52;
  }
  __syncthreads();

  // ---- b/G: thread = (p, at) ----
  if (tid < NPERM * NATOM) {
    int p = tid / NATOM, at = tid % NATOM;
    const int* gt = &gtab[(p * NATOM + at) * 20];
    const float* dfp = &diffS[p][0];
    float g0 = 0, g1 = 0, g2 = 0, b0 = 0, b1 = 0, b2 = 0;
#pragma unroll
    for (int i = 0; i < 20; ++i) {
      int v = gt[i];
      int d = v & 511, tw = (v >> 9) & 511;
      float s = (v & (1 << 18)) ? -1.0f : 1.0f;
      float fd = s * dfp[d], ftw = s * dfp[tw];
      float4 rn = Rdn4[d];
      float4 rj = Rdj4[d];
      g0 += rn.x * fd; g1 += rn.y * fd; g2 += rn.z * fd;
      b0 += rj.x * ftw; b1 += rj.y * ftw; b2 += rj.z * ftw;
    }
    float c1 = c1s[p];
    GT[3 * at + 0][p] = c1 * g0;
    GT[3 * at + 1][p] = c1 * g1;
    GT[3 * at + 2][p] = c1 * g2;
    bT[3 * at + 0][p] = b0;
    bT[3 * at + 1][p] = b1;
    bT[3 * at + 2][p] = b2;
  }
  __syncthreads();

  // ---- final: thread = (A,B) 3x3 tile; term2 operands from GLOBAL (L1), not LDS ----
  const size_t base = (size_t)n * DIMI * (NCOLS * DIMI) + (size_t)jc * DIMI;
#pragma unroll
  for (int pass = 0; pass < 2; ++pass) {
    int pid = tid + pass * 252;
    if (tid < 252 && pid < NATOM * NATOM) {
      int A = pid / NATOM, B = pid % NATOM;
      float acc[3][3];
#pragma unroll
      for (int c = 0; c < 3; ++c)
#pragma unroll
        for (int e = 0; e < 3; ++e) acc[c][e] = 0.f;

      // term2: acc += coef * Rdn[d,:] (x) Rdj[dd,:], coef = (+/-) c2s[p] via sign XOR
      int o0 = entOff[pid], o1 = entOff[pid + 1];
      for (int o = o0; o < o1; ++o) {
        int v = ents[o];
        int td = v & 1023, tdd = (v >> 10) & 1023, p = (v >> 20) & 15;
        unsigned sgn = ((unsigned)v & 0x01000000u) << 7;  // bit24 -> bit31
        float c2 = __uint_as_float(__float_as_uint(c2s[p]) ^ sgn);
        float rjx = gj[tdd], rjy = gj[tdd + 1], rjz = gj[tdd + 2];
        float rnx = gn[td], rny = gn[td + 1], rnz = gn[td + 2];
        float w0 = c2 * rjx, w1 = c2 * rjy, w2 = c2 * rjz;
        acc[0][0] += rnx * w0; acc[0][1] += rnx * w1; acc[0][2] += rnx * w2;
        acc[1][0] += rny * w0; acc[1][1] += rny * w1; acc[1][2] += rny * w2;
        acc[2][0] += rnz * w0; acc[2][1] += rnz * w1; acc[2][2] += rnz * w2;
      }

      // term1: acc[cg][cb] += sum_p G[3A+cg][p] * b[3B+cb][p]  (LDS float4 rows)
#pragma unroll
      for (int cg = 0; cg < 3; ++cg) {
        const float4* gp = (const float4*)&GT[3 * A + cg][0];
        float4 ga = gp[0], gb = gp[1], gc = gp[2];
#pragma unroll
        for (int cb = 0; cb < 3; ++cb) {
          const float4* bp = (const float4*)&bT[3 * B + cb][0];
          float4 ba = bp[0], bb = bp[1], bc = bp[2];
          acc[cg][cb] += ga.x * ba.x + ga.y * ba.y + ga.z * ba.z + ga.w * ba.w
                       + gb.x * bb.x + gb.y * bb.y + gb.z * bb.z + gb.w * bb.w
                       + gc.x * bc.x + gc.y * bc.y + gc.z * bc.z + gc.w * bc.w;
        }
      }

#pragma unroll
      for (int cg = 0; cg < 3; ++cg) {
        float* op = out + base + (size_t)(3 * A + cg) * (NCOLS * DIMI) + 3 * B;
        op[0] = acc[cg][0]; op[1] = acc[cg][1]; op[2] = acc[cg][2];
      }
    }
  }
}

extern "C" void kernel_launch(void* const* d_in, const int* in_sizes, int n_in,
                              void* d_out, int out_size, void* d_ws, size_t ws_size,
                              hipStream_t stream) {
  const float* R_desc = (const float*)d_in[0];
  const float* R_d_desc = (const float*)d_in[1];
  const int* tril = (const int*)d_in[2];
  const int* j_idxs = (const int*)d_in[3];
  float* out = (float*)d_out;
  int* ws = (int*)d_ws;

  hipLaunchKernelGGL(gdml_setup, dim3(1), dim3(512), 0, stream, tril, ws);
  hipLaunchKernelGGL(gdml_main, dim3(NTRAIN * NCOLS), dim3(256), 0, stream,
                     R_desc, R_d_desc, j_idxs, ws, out);
}

// Round 6
// 491.165 us; speedup vs baseline: 1.6642x; 1.4180x over previous
//
#include <hip/hip_runtime.h>
#include <math.h>

#define NTRAIN 2000
#define DIMD 210
#define DIMI 63
#define NPERM 12
#define NCOLS 8
#define NATOM 21
#define SIGF 10.0f

// ws layout (ints):
#define WS_PERM      0        // 2520
#define WS_GTAB      6300     // 5040 (gap below kept for layout compat)
#define WS_ENTOFF    11340    // 442
#define WS_ENTS      11782    // 10080
#define WS_TILEMAP   21862    // 441
// total 22303 ints (~89 KB)

// ---------------- setup: fully parallel, LDS-staged ----------------
__global__ __launch_bounds__(512) void gdml_setup(const int* __restrict__ tril,
                                                  int* __restrict__ ws) {
  __shared__ int sPerm[NPERM * DIMD];
  __shared__ int sInv[NPERM * DIMD];
  __shared__ int sRow[DIMD], sCol[DIMD];
  __shared__ int sPairs[NATOM * 20], sNeg[NATOM * 20];
  __shared__ int sCnt[441];
  __shared__ int sScan[512];
  __shared__ int sOff[442];

  const int tid = threadIdx.x;

  for (int d = tid; d < DIMD; d += 512) {
    int a = 1;
    while ((a * (a + 1)) / 2 <= d) a++;
    sRow[d] = a;
    sCol[d] = d - (a * (a - 1)) / 2;
  }
  for (int idx = tid; idx < NPERM * DIMD; idx += 512) {
    int p = idx / DIMD, d = idx % DIMD;
    sPerm[idx] = tril[d * NPERM + p] % DIMD;
  }
  __syncthreads();
  for (int idx = tid; idx < NPERM * DIMD; idx += 512) {
    int p = idx / DIMD;
    sInv[p * DIMD + sPerm[idx]] = idx % DIMD;
  }
  if (tid < NATOM) {
    int t = tid, c = 0;
    for (int d = 0; d < DIMD; ++d) {
      if (sRow[d] == t)      { sPairs[t * 20 + c] = d; sNeg[t * 20 + c] = 0; c++; }
      else if (sCol[d] == t) { sPairs[t * 20 + c] = d; sNeg[t * 20 + c] = 1; c++; }
    }
  }
  __syncthreads();

  for (int idx = tid; idx < NPERM * DIMD; idx += 512) ws[WS_PERM + idx] = sPerm[idx];
  // gtab[(p*21+at)*20+i] = d | tw<<9 | neg<<18
  for (int idx = tid; idx < NPERM * NATOM * 20; idx += 512) {
    int p = idx / (NATOM * 20);
    int r = idx % (NATOM * 20);
    int d = sPairs[r], neg = sNeg[r];
    int tw = sInv[p * DIMD + d];
    ws[WS_GTAB + idx] = d | (tw << 9) | (neg << 18);
  }

  // CSR counts per (A,B)
  for (int q = tid; q < 441; q += 512) {
    int A = q / NATOM, B = q % NATOM, c = 0;
    for (int i = 0; i < 20; ++i) {
      int d = sPairs[A * 20 + i];
      for (int p = 0; p < NPERM; ++p) {
        int dd = sPerm[p * DIMD + d];
        c += (sRow[dd] == B) + (sCol[dd] == B);
      }
    }
    sCnt[q] = c;
  }
  __syncthreads();

  // Hillis-Steele scan over 441
  sScan[tid] = (tid < 441) ? sCnt[tid] : 0;
  __syncthreads();
  for (int s = 1; s < 512; s <<= 1) {
    int v = (tid >= s) ? sScan[tid - s] : 0;
    __syncthreads();
    sScan[tid] += v;
    __syncthreads();
  }
  if (tid == 0) sOff[0] = 0;
  if (tid < 441) sOff[tid + 1] = sScan[tid];
  __syncthreads();
  for (int q = tid; q < 442; q += 512) ws[WS_ENTOFF + q] = sOff[q];

  // tileMap: rank tiles by entry count DESC (stable tie-break by q) for wave balance
  for (int q = tid; q < 441; q += 512) {
    int c = sCnt[q], r = 0;
    for (int q2 = 0; q2 < 441; ++q2) {
      int c2v = sCnt[q2];
      r += (c2v > c) || (c2v == c && q2 < q);
    }
    ws[WS_TILEMAP + r] = q;
  }

  // fill entries: v = d | dd<<9 | p<<18 | negbit<<22 (negbit=1 -> coef = -c2)
  for (int q = tid; q < 441; q += 512) {
    int A = q / NATOM, B = q % NATOM;
    int o = sOff[q];
    for (int i = 0; i < 20; ++i) {
      int d = sPairs[A * 20 + i];
      int negA = sNeg[A * 20 + i];
      for (int p = 0; p < NPERM; ++p) {
        int dd = sPerm[p * DIMD + d];
        int base = d | (dd << 9) | (p << 18);
        if (sRow[dd] == B) ws[WS_ENTS + (o++)] = base | ((negA ^ 1) << 22);
        if (sCol[dd] == B) ws[WS_ENTS + (o++)] = base | (negA << 22);
      }
    }
  }
}

// ---------------- main kernel: one block per (n, j-column) ----------------
__global__ __launch_bounds__(256, 4) void gdml_main(
    const float* __restrict__ R_desc, const float* __restrict__ R_d_desc,
    const int* __restrict__ j_idxs, const int* __restrict__ ws,
    float* __restrict__ out) {
  const int* perm    = ws + WS_PERM;
  const int* gtab    = ws + WS_GTAB;
  const int* entOff  = ws + WS_ENTOFF;
  const int* ents    = ws + WS_ENTS;
  const int* tileMap = ws + WS_TILEMAP;

  const int bid = blockIdx.x;
  const int jc = bid & 7;
  const int n = bid >> 3;
  const int tid = threadIdx.x;
  const int j = j_idxs[jc];

  __shared__ __align__(16) float diffS[NPERM][DIMD];               // 10,080 B
  __shared__ float Rdnx[DIMD], Rdny[DIMD], Rdnz[DIMD];             // 2,520 (SoA)
  __shared__ float Rdjx[DIMD], Rdjy[DIMD], Rdjz[DIMD];             // 2,520
  __shared__ float Rn[DIMD], Rj[DIMD];                             // 1,680
  __shared__ __align__(16) float GT[NPERM][64], bT[NPERM][64];     // 6,144 (p-major)
  __shared__ float c1s[NPERM], c2s[NPERM];
  __shared__ float partial[252];
  // ~24 KB -> 6 blocks/CU

  // ---- stage inputs ----
  for (int i = tid; i < DIMD; i += 256) {
    Rn[i] = R_desc[(size_t)n * DIMD + i];
    Rj[i] = R_desc[(size_t)j * DIMD + i];
  }
  if (tid < DIMD) {
    const float* gn = R_d_desc + (size_t)n * (DIMD * 3) + 3 * tid;
    const float* gj = R_d_desc + (size_t)j * (DIMD * 3) + 3 * tid;
    Rdnx[tid] = gn[0]; Rdny[tid] = gn[1]; Rdnz[tid] = gn[2];
    Rdjx[tid] = gj[0]; Rdjy[tid] = gj[1]; Rdjz[tid] = gj[2];
  }
  __syncthreads();

  // ---- diff[p][d] = Rn[d] - Rj[perm[p][d]] ----
  for (int idx = tid; idx < NPERM * DIMD; idx += 256) {
    int d = idx % DIMD;
    ((float*)diffS)[idx] = Rn[d] - Rj[perm[idx]];
  }
  __syncthreads();

  // ---- norms ----
  if (tid < 252) {
    int p = tid / 21, seg = tid % 21;
    const float* dp = &diffS[p][seg * 10];
    float s = 0.f;
#pragma unroll
    for (int i = 0; i < 10; ++i) s += dp[i] * dp[i];
    partial[tid] = s;
  }
  __syncthreads();
  if (tid < NPERM) {
    float s = 0.f;
#pragma unroll
    for (int i = 0; i < 21; ++i) s += partial[tid * 21 + i];
    float nrm = sqrtf(5.0f) * sqrtf(s);
    float mat52 = expf(-nrm / SIGF) * (5.0f / (3.0f * SIGF * SIGF * SIGF * SIGF));
    c1s[tid] = 5.0f * mat52;
    c2s[tid] = (SIGF * SIGF + SIGF * nrm) * mat52;
  }
  __syncthreads();

  // ---- b/G: thread = (p, at); writes p-major GT/bT (stride-3 b32, conflict-free) ----
  if (tid < NPERM * NATOM) {
    int p = tid / NATOM, at = tid % NATOM;
    const int* gt = &gtab[(p * NATOM + at) * 20];
    const float* dfp = &diffS[p][0];
    float g0 = 0, g1 = 0, g2 = 0, b0 = 0, b1 = 0, b2 = 0;
#pragma unroll
    for (int i = 0; i < 20; ++i) {
      int v = gt[i];
      int d = v & 511, tw = (v >> 9) & 511;
      float s = (v & (1 << 18)) ? -1.0f : 1.0f;
      float fd = s * dfp[d], ftw = s * dfp[tw];
      g0 += Rdnx[d] * fd; g1 += Rdny[d] * fd; g2 += Rdnz[d] * fd;
      b0 += Rdjx[d] * ftw; b1 += Rdjy[d] * ftw; b2 += Rdjz[d] * ftw;
    }
    float c1 = c1s[p];
    GT[p][3 * at + 0] = c1 * g0;
    GT[p][3 * at + 1] = c1 * g1;
    GT[p][3 * at + 2] = c1 * g2;
    bT[p][3 * at + 0] = b0;
    bT[p][3 * at + 1] = b1;
    bT[p][3 * at + 2] = b2;
  }
  __syncthreads();

  // ---- final: rank-sorted (A,B) 3x3 tiles; all operands LDS SoA b32 ----
  const size_t base = (size_t)n * DIMI * (NCOLS * DIMI) + (size_t)jc * DIMI;
#pragma unroll
  for (int pass = 0; pass < 2; ++pass) {
    int rank = tid + pass * 256;
    if (rank < NATOM * NATOM) {
      int q = tileMap[rank];
      int A = q / NATOM, B = q % NATOM;
      float acc[3][3];
#pragma unroll
      for (int c = 0; c < 3; ++c)
#pragma unroll
        for (int e = 0; e < 3; ++e) acc[c][e] = 0.f;

      // term2: acc += (+/-)c2[p] * Rdn[d,:] (x) Rdj[dd,:]
      int o0 = entOff[q], o1 = entOff[q + 1];
      for (int o = o0; o < o1; ++o) {
        int v = ents[o];
        int d = v & 511, dd = (v >> 9) & 511, p = (v >> 18) & 15;
        unsigned sgn = ((unsigned)(v & (1 << 22))) << 9;  // bit22 -> bit31
        float c2 = __uint_as_float(__float_as_uint(c2s[p]) ^ sgn);
        float rnx = Rdnx[d], rny = Rdny[d], rnz = Rdnz[d];
        float w0 = c2 * Rdjx[dd], w1 = c2 * Rdjy[dd], w2 = c2 * Rdjz[dd];
        acc[0][0] += rnx * w0; acc[0][1] += rnx * w1; acc[0][2] += rnx * w2;
        acc[1][0] += rny * w0; acc[1][1] += rny * w1; acc[1][2] += rny * w2;
        acc[2][0] += rnz * w0; acc[2][1] += rnz * w1; acc[2][2] += rnz * w2;
      }

      // term1: acc[cg][cb] += sum_p GT[p][3A+cg] * bT[p][3B+cb] (conflict-free b32)
#pragma unroll
      for (int p = 0; p < NPERM; ++p) {
        float ga = GT[p][3 * A + 0], gb = GT[p][3 * A + 1], gc = GT[p][3 * A + 2];
        float ba = bT[p][3 * B + 0], bb = bT[p][3 * B + 1], bc = bT[p][3 * B + 2];
        acc[0][0] += ga * ba; acc[0][1] += ga * bb; acc[0][2] += ga * bc;
        acc[1][0] += gb * ba; acc[1][1] += gb * bb; acc[1][2] += gb * bc;
        acc[2][0] += gc * ba; acc[2][1] += gc * bb; acc[2][2] += gc * bc;
      }

#pragma unroll
      for (int cg = 0; cg < 3; ++cg) {
        float* op = out + base + (size_t)(3 * A + cg) * (NCOLS * DIMI) + 3 * B;
        op[0] = acc[cg][0]; op[1] = acc[cg][1]; op[2] = acc[cg][2];
      }
    }
  }
}

extern "C" void kernel_launch(void* const* d_in, const int* in_sizes, int n_in,
                              void* d_out, int out_size, void* d_ws, size_t ws_size,
                              hipStream_t stream) {
  const float* R_desc = (const float*)d_in[0];
  const float* R_d_desc = (const float*)d_in[1];
  const int* tril = (const int*)d_in[2];
  const int* j_idxs = (const int*)d_in[3];
  float* out = (float*)d_out;
  int* ws = (int*)d_ws;

  hipLaunchKernelGGL(gdml_setup, dim3(1), dim3(512), 0, stream, tril, ws);
  hipLaunchKernelGGL(gdml_main, dim3(NTRAIN * NCOLS), dim3(256), 0, stream,
                     R_desc, R_d_desc, j_idxs, ws, out);
}